// Round 3
// baseline (2042.349 us; speedup 1.0000x reference)
//
#include <hip/hip_runtime.h>

#define Bq 2
#define Lq 1024
#define Dq 1024
#define Hq 16
#define HDq 64
#define HIDq 4096
#define Mq (Bq*Lq)   // 2048

typedef __bf16 bf16x8 __attribute__((ext_vector_type(8)));
typedef float floatx4 __attribute__((ext_vector_type(4)));

__device__ __forceinline__ float us2f(unsigned short u){
  unsigned v = ((unsigned)u) << 16;
  return __builtin_bit_cast(float, v);
}
__device__ __forceinline__ unsigned short f2us(float f){
  unsigned u = __builtin_bit_cast(unsigned, f);
  u = u + 0x7fffu + ((u >> 16) & 1u);      // RNE to bf16
  return (unsigned short)(u >> 16);
}
__device__ __forceinline__ float lo2f(unsigned u){ return __builtin_bit_cast(float, u << 16); }
__device__ __forceinline__ float hi2f(unsigned u){ return __builtin_bit_cast(float, u & 0xffff0000u); }

// ---------------- f32 -> bf16 conversion (weights), 4 arrays per launch ----------------
__global__ __launch_bounds__(256) void cvt4_kernel(
    const float* __restrict__ s0, const float* __restrict__ s1,
    const float* __restrict__ s2, const float* __restrict__ s3,
    unsigned short* __restrict__ d0, unsigned short* __restrict__ d1,
    unsigned short* __restrict__ d2, unsigned short* __restrict__ d3,
    int n)
{
  const int a = blockIdx.y;
  const float* s = (a==0) ? s0 : (a==1) ? s1 : (a==2) ? s2 : s3;
  unsigned short* d = (a==0) ? d0 : (a==1) ? d1 : (a==2) ? d2 : d3;
  const int i = (blockIdx.x * 256 + threadIdx.x) * 8;
  if (i >= n) return;
  float4 v0 = ((const float4*)(s + i))[0];
  float4 v1 = ((const float4*)(s + i))[1];
  ushort4 o0, o1;
  o0.x=f2us(v0.x); o0.y=f2us(v0.y); o0.z=f2us(v0.z); o0.w=f2us(v0.w);
  o1.x=f2us(v1.x); o1.y=f2us(v1.y); o1.z=f2us(v1.z); o1.w=f2us(v1.w);
  ((ushort4*)(d + i))[0] = o0;
  ((ushort4*)(d + i))[1] = o1;
}

// ---------------- complex LayerNorm: f32 in, bf16 out; one block per row ----------------
__global__ __launch_bounds__(256) void cln_kernel(
    const float* __restrict__ xr, const float* __restrict__ xi,
    const float* __restrict__ gr, const float* __restrict__ gi,
    const float* __restrict__ br, const float* __restrict__ bi,
    unsigned short* __restrict__ outr, unsigned short* __restrict__ outi)
{
  const int row = blockIdx.x;
  const int t = threadIdx.x;
  const int lane = t & 63, wv = t >> 6;
  __shared__ float sred[8];

  float4 v4r = ((const float4*)(xr + (size_t)row*Dq))[t];
  float4 v4i = ((const float4*)(xi + (size_t)row*Dq))[t];
  float vr[4] = {v4r.x, v4r.y, v4r.z, v4r.w};
  float vi[4] = {v4i.x, v4i.y, v4i.z, v4i.w};
  float sr = vr[0]+vr[1]+vr[2]+vr[3];
  float si = vi[0]+vi[1]+vi[2]+vi[3];
  #pragma unroll
  for (int o=32;o>0;o>>=1){ sr += __shfl_down(sr,o,64); si += __shfl_down(si,o,64); }
  if (lane==0){ sred[wv]=sr; sred[4+wv]=si; }
  __syncthreads();
  float mr = (sred[0]+sred[1]+sred[2]+sred[3]) * (1.0f/Dq);
  float mi = (sred[4]+sred[5]+sred[6]+sred[7]) * (1.0f/Dq);
  float cr[4], ci[4], vs = 0.f;
  #pragma unroll
  for (int j=0;j<4;++j){ cr[j]=vr[j]-mr; ci[j]=vi[j]-mi; vs += cr[j]*cr[j]+ci[j]*ci[j]; }
  #pragma unroll
  for (int o=32;o>0;o>>=1) vs += __shfl_down(vs,o,64);
  __syncthreads();
  if (lane==0) sred[wv]=vs;
  __syncthreads();
  float var = (sred[0]+sred[1]+sred[2]+sred[3]) * (1.0f/Dq);
  float inv = rsqrtf(var + 1e-6f);

  float4 g4r = ((const float4*)gr)[t];
  float4 g4i = ((const float4*)gi)[t];
  float4 b4r = ((const float4*)br)[t];
  float4 b4i = ((const float4*)bi)[t];
  float grf[4] = {g4r.x,g4r.y,g4r.z,g4r.w};
  float gif[4] = {g4i.x,g4i.y,g4i.z,g4i.w};
  float brf[4] = {b4r.x,b4r.y,b4r.z,b4r.w};
  float bif[4] = {b4i.x,b4i.y,b4i.z,b4i.w};
  ushort4 o_r, o_i;
  unsigned short orr[4], oii[4];
  #pragma unroll
  for (int j=0;j<4;++j){
    float nr = cr[j]*inv, ni = ci[j]*inv;
    orr[j] = f2us(nr*grf[j] - ni*gif[j] + brf[j]);
    oii[j] = f2us(nr*gif[j] + ni*grf[j] + bif[j]);
  }
  o_r.x=orr[0]; o_r.y=orr[1]; o_r.z=orr[2]; o_r.w=orr[3];
  o_i.x=oii[0]; o_i.y=oii[1]; o_i.z=oii[2]; o_i.w=oii[3];
  ((ushort4*)(outr + (size_t)row*Dq))[t] = o_r;
  ((ushort4*)(outi + (size_t)row*Dq))[t] = o_i;
}

// ---------------- complex GEMM: C = A @ W^T (complex), MFMA bf16 ----------------
// A: [M,K] bf16 (r,i)  W: [N,K] bf16 (r,i)
// EPI: 0 plain bf16 store; 1 +bias+resid(f32)->f32; 2 +bias+ModReLU->bf16; 3 +bias+resid(f32)->f32
template<int EPI, bool ROPE>
__global__ __launch_bounds__(256,2) void cgemm_kernel(
    const unsigned short* __restrict__ Ar, const unsigned short* __restrict__ Ai,
    const unsigned short* __restrict__ Wr, const unsigned short* __restrict__ Wi,
    void* __restrict__ Cr, void* __restrict__ Ci,
    const float* __restrict__ biasR, const float* __restrict__ biasI,
    const float* __restrict__ resR, const float* __restrict__ resI,
    const float* __restrict__ modb,
    int Ndim, int Kdim)
{
  const int t = threadIdx.x;
  const int wv = t >> 6, lane = t & 63;
  const int quad = lane >> 4, l15 = lane & 15;
  const int m0 = blockIdx.x * 64, n0 = blockIdx.y * 64;

  __shared__ __align__(16) unsigned short sAr[64*40], sAi[64*40], sWr[64*40], sWi[64*40];

  floatx4 accRR[4], accII[4], accRI[4], accIR[4];
  floatx4 zero = {0.f,0.f,0.f,0.f};
  #pragma unroll
  for (int i=0;i<4;++i){ accRR[i]=zero; accII[i]=zero; accRI[i]=zero; accIR[i]=zero; }

  const int lr = t >> 2;          // staging row 0..63
  const int lc = (t & 3) * 8;     // staging col 0,8,16,24
  const unsigned short* pAr = Ar + (size_t)(m0+lr)*Kdim + lc;
  const unsigned short* pAi = Ai + (size_t)(m0+lr)*Kdim + lc;
  const unsigned short* pWr = Wr + (size_t)(n0+lr)*Kdim + lc;
  const unsigned short* pWi = Wi + (size_t)(n0+lr)*Kdim + lc;
  const int ldso = lr*40 + lc;
  const int arow = wv*16 + l15;

  const int nk = Kdim >> 5;
  for (int kk=0; kk<nk; ++kk){
    uint4 va = *(const uint4*)(pAr + kk*32);
    uint4 vb = *(const uint4*)(pAi + kk*32);
    uint4 vc = *(const uint4*)(pWr + kk*32);
    uint4 vd = *(const uint4*)(pWi + kk*32);
    __syncthreads();
    *(uint4*)&sAr[ldso] = va;
    *(uint4*)&sAi[ldso] = vb;
    *(uint4*)&sWr[ldso] = vc;
    *(uint4*)&sWi[ldso] = vd;
    __syncthreads();
    bf16x8 fAr = *(const bf16x8*)&sAr[arow*40 + quad*8];
    bf16x8 fAi = *(const bf16x8*)&sAi[arow*40 + quad*8];
    #pragma unroll
    for (int tt=0; tt<4; ++tt){
      const int brow = tt*16 + l15;
      bf16x8 fWr = *(const bf16x8*)&sWr[brow*40 + quad*8];
      bf16x8 fWi = *(const bf16x8*)&sWi[brow*40 + quad*8];
      accRR[tt] = __builtin_amdgcn_mfma_f32_16x16x32_bf16(fAr, fWr, accRR[tt], 0,0,0);
      accII[tt] = __builtin_amdgcn_mfma_f32_16x16x32_bf16(fAi, fWi, accII[tt], 0,0,0);
      accRI[tt] = __builtin_amdgcn_mfma_f32_16x16x32_bf16(fAr, fWi, accRI[tt], 0,0,0);
      accIR[tt] = __builtin_amdgcn_mfma_f32_16x16x32_bf16(fAi, fWr, accIR[tt], 0,0,0);
    }
  }

  float cr[4][4], ci[4][4];
  #pragma unroll
  for (int tt=0; tt<4; ++tt)
    #pragma unroll
    for (int r=0; r<4; ++r){
      cr[tt][r] = accRR[tt][r] - accII[tt][r];
      ci[tt][r] = accRI[tt][r] + accIR[tt][r];
    }

  if (ROPE){
    // wave covers one full 64-wide head: hd = tt*16+l15; partner hd+32 is subtile tt+2
    #pragma unroll
    for (int tt=0; tt<2; ++tt){
      const int j = tt*16 + l15;                // rope freq index 0..31
      const float invf = powf(10000.0f, -(float)j * (1.0f/32.0f));
      #pragma unroll
      for (int r=0; r<4; ++r){
        const int gm = m0 + wv*16 + quad*4 + r;
        const int l = gm & (Lq-1);
        float s, c;
        sincosf((float)l * invf, &s, &c);
        float xr_ = cr[tt][r], yr_ = cr[tt+2][r];
        cr[tt][r]   = xr_*c - yr_*s;
        cr[tt+2][r] = yr_*c + xr_*s;
        float xi_ = ci[tt][r], yi_ = ci[tt+2][r];
        ci[tt][r]   = xi_*c - yi_*s;
        ci[tt+2][r] = yi_*c + xi_*s;
      }
    }
  }

  #pragma unroll
  for (int tt=0; tt<4; ++tt){
    const int gn = n0 + tt*16 + l15;
    float bR = 0.f, bI = 0.f, mb = 0.f;
    if (EPI >= 1){ bR = biasR[gn]; bI = biasI[gn]; }
    if (EPI == 2){ mb = modb[gn]; }
    #pragma unroll
    for (int r=0; r<4; ++r){
      const int gm = m0 + wv*16 + quad*4 + r;
      const size_t idx = (size_t)gm*Ndim + gn;
      float vr_ = cr[tt][r] + bR, vi_ = ci[tt][r] + bI;
      if (EPI == 1 || EPI == 3){ vr_ += resR[idx]; vi_ += resI[idx]; }
      if (EPI == 2){
        float mag = sqrtf(vr_*vr_ + vi_*vi_);
        float safe = (mag > 0.f) ? mag : 1.0f;
        float act = fmaxf(mag + mb, 0.f);
        float sc = act / safe;
        vr_ *= sc; vi_ *= sc;
      }
      if (EPI == 0 || EPI == 2){
        ((unsigned short*)Cr)[idx] = f2us(vr_);
        ((unsigned short*)Ci)[idx] = f2us(vi_);
      } else {
        ((float*)Cr)[idx] = vr_;
        ((float*)Ci)[idx] = vi_;
      }
    }
  }
}

// ---------------- attention: one block per (b,h,q) row; bf16 in/out ----------------
__global__ __launch_bounds__(256) void attn_kernel(
    const unsigned short* __restrict__ Qr, const unsigned short* __restrict__ Qi,
    const unsigned short* __restrict__ Kr, const unsigned short* __restrict__ Ki,
    const unsigned short* __restrict__ Vr, const unsigned short* __restrict__ Vi,
    unsigned short* __restrict__ Or, unsigned short* __restrict__ Oi)
{
  const int id = blockIdx.x;
  const int q  = id & (Lq-1);
  const int bh = id >> 10;
  const int h  = bh & (Hq-1);
  const int b  = bh >> 4;
  const int t  = threadIdx.x;

  __shared__ float sQr[HDq], sQi[HDq];
  __shared__ float sS[Lq];
  __shared__ float sred[8];
  __shared__ float sOr[4][HDq], sOi[4][HDq];

  const size_t qbase = (size_t)(b*Lq+q)*Dq + h*HDq;
  if (t < 64)        sQr[t]    = us2f(Qr[qbase + t])    * 0.125f;   // fold SCALE
  else if (t < 128)  sQi[t-64] = us2f(Qi[qbase + t-64]) * 0.125f;
  __syncthreads();

  float lm = -1e30f;
  for (int m = t; m <= q; m += 256){
    const size_t kb = (size_t)(b*Lq+m)*Dq + h*HDq;
    const uint4* kr4 = (const uint4*)(Kr + kb);
    const uint4* ki4 = (const uint4*)(Ki + kb);
    float sum = 0.f;
    #pragma unroll
    for (int c=0; c<8; ++c){
      uint4 u = kr4[c];
      const float* qp = &sQr[c*8];
      sum += qp[0]*lo2f(u.x) + qp[1]*hi2f(u.x)
           + qp[2]*lo2f(u.y) + qp[3]*hi2f(u.y)
           + qp[4]*lo2f(u.z) + qp[5]*hi2f(u.z)
           + qp[6]*lo2f(u.w) + qp[7]*hi2f(u.w);
      uint4 w = ki4[c];
      const float* qq = &sQi[c*8];
      sum += qq[0]*lo2f(w.x) + qq[1]*hi2f(w.x)
           + qq[2]*lo2f(w.y) + qq[3]*hi2f(w.y)
           + qq[4]*lo2f(w.z) + qq[5]*hi2f(w.z)
           + qq[6]*lo2f(w.w) + qq[7]*hi2f(w.w);
    }
    sS[m] = sum;
    lm = fmaxf(lm, sum);
  }
  #pragma unroll
  for (int o=32;o>0;o>>=1) lm = fmaxf(lm, __shfl_xor(lm,o,64));
  if ((t&63)==0) sred[t>>6] = lm;
  __syncthreads();
  const float mx = fmaxf(fmaxf(sred[0],sred[1]), fmaxf(sred[2],sred[3]));

  float ls = 0.f;
  for (int m = t; m <= q; m += 256){
    float e = __expf(sS[m] - mx);
    sS[m] = e;
    ls += e;
  }
  #pragma unroll
  for (int o=32;o>0;o>>=1) ls += __shfl_xor(ls,o,64);
  __syncthreads();
  if ((t&63)==0) sred[t>>6] = ls;
  __syncthreads();
  const float inv = 1.0f / (sred[0]+sred[1]+sred[2]+sred[3]);

  const int d = t & 63, g = t >> 6;
  float or_ = 0.f, oi_ = 0.f;
  for (int m = g; m <= q; m += 4){
    const size_t vb = (size_t)(b*Lq+m)*Dq + h*HDq + d;
    const float p = sS[m];
    or_ += p * us2f(Vr[vb]);
    oi_ += p * us2f(Vi[vb]);
  }
  sOr[g][d] = or_;
  sOi[g][d] = oi_;
  __syncthreads();
  if (g == 0){
    float o = (sOr[0][d]+sOr[1][d]+sOr[2][d]+sOr[3][d]) * inv;
    Or[qbase + d] = f2us(o);
  } else if (g == 1){
    float o = (sOi[0][d]+sOi[1][d]+sOi[2][d]+sOi[3][d]) * inv;
    Oi[qbase + d] = f2us(o);
  }
}

// ---------------- launch ----------------
extern "C" void kernel_launch(void* const* d_in, const int* in_sizes, int n_in,
                              void* d_out, int out_size, void* d_ws, size_t ws_size,
                              hipStream_t stream)
{
  const float* x_r    = (const float*)d_in[0];
  const float* x_i    = (const float*)d_in[1];
  const float* Wq_r   = (const float*)d_in[2];
  const float* Wq_i   = (const float*)d_in[3];
  const float* Wk_r   = (const float*)d_in[4];
  const float* Wk_i   = (const float*)d_in[5];
  const float* Wv_r   = (const float*)d_in[6];
  const float* Wv_i   = (const float*)d_in[7];
  const float* Wo_r   = (const float*)d_in[8];
  const float* Wo_i   = (const float*)d_in[9];
  const float* bo_r   = (const float*)d_in[10];
  const float* bo_i   = (const float*)d_in[11];
  const float* ln1_gr = (const float*)d_in[12];
  const float* ln1_gi = (const float*)d_in[13];
  const float* ln1_br = (const float*)d_in[14];
  const float* ln1_bi = (const float*)d_in[15];
  const float* ln2_gr = (const float*)d_in[16];
  const float* ln2_gi = (const float*)d_in[17];
  const float* ln2_br = (const float*)d_in[18];
  const float* ln2_bi = (const float*)d_in[19];
  const float* W1_r   = (const float*)d_in[20];
  const float* W1_i   = (const float*)d_in[21];
  const float* b1_r   = (const float*)d_in[22];
  const float* b1_i   = (const float*)d_in[23];
  const float* W2_r   = (const float*)d_in[24];
  const float* W2_i   = (const float*)d_in[25];
  const float* b2_r   = (const float*)d_in[26];
  const float* b2_i   = (const float*)d_in[27];
  const float* mod_b  = (const float*)d_in[28];

  char* wsb = (char*)d_ws;
  const size_t MB = 1024*1024;
  // --- weights, bf16 (converted each call): 0..48 MB ---
  unsigned short* bWq_r = (unsigned short*)(wsb + 0*MB);    // D*D bf16 = 2MB each
  unsigned short* bWq_i = (unsigned short*)(wsb + 2*MB);
  unsigned short* bWk_r = (unsigned short*)(wsb + 4*MB);
  unsigned short* bWk_i = (unsigned short*)(wsb + 6*MB);
  unsigned short* bWv_r = (unsigned short*)(wsb + 8*MB);
  unsigned short* bWv_i = (unsigned short*)(wsb + 10*MB);
  unsigned short* bWo_r = (unsigned short*)(wsb + 12*MB);
  unsigned short* bWo_i = (unsigned short*)(wsb + 14*MB);
  unsigned short* bW1_r = (unsigned short*)(wsb + 16*MB);   // HID*D bf16 = 8MB each
  unsigned short* bW1_i = (unsigned short*)(wsb + 24*MB);
  unsigned short* bW2_r = (unsigned short*)(wsb + 32*MB);
  unsigned short* bW2_i = (unsigned short*)(wsb + 40*MB);
  // --- activations: 48..96 MB ([M,D] bf16 = 4MB; [M,HID] bf16 = 16MB) ---
  unsigned short* hr  = (unsigned short*)(wsb + 48*MB);
  unsigned short* hi_ = (unsigned short*)(wsb + 52*MB);
  unsigned short* Qr  = (unsigned short*)(wsb + 56*MB);
  unsigned short* Qi  = (unsigned short*)(wsb + 60*MB);
  unsigned short* Kr  = (unsigned short*)(wsb + 64*MB);
  unsigned short* Ki  = (unsigned short*)(wsb + 68*MB);
  unsigned short* Vr  = (unsigned short*)(wsb + 72*MB);
  unsigned short* Vi  = (unsigned short*)(wsb + 76*MB);
  unsigned short* Or  = hr;                               // hr/hi dead after QKV gemms
  unsigned short* Oi  = hi_;
  unsigned short* h2r = Qr;                               // Q dead after attn
  unsigned short* h2i = Qi;
  unsigned short* fr  = (unsigned short*)(wsb + 64*MB);   // 64..80 over K (dead after attn)
  unsigned short* fi  = (unsigned short*)(wsb + 80*MB);   // 80..96 over V (dead after attn)

  float* outR = (float*)d_out;                            // ar lives here (f32)
  float* outI = outR + (size_t)Mq*Dq;                     // ai lives here (f32)

  const dim3 blk(256);
  const dim3 gD(Mq/64, Dq/64);     // 32 x 16
  const dim3 gH(Mq/64, HIDq/64);   // 32 x 64

  // 0. weight conversion f32 -> bf16
  const int nDD = Dq*Dq;           // 1M elems
  const int nDH = Dq*HIDq;         // 4M elems
  cvt4_kernel<<<dim3(nDD/2048, 4), blk, 0, stream>>>(Wq_r, Wq_i, Wk_r, Wk_i,
      bWq_r, bWq_i, bWk_r, bWk_i, nDD);
  cvt4_kernel<<<dim3(nDD/2048, 4), blk, 0, stream>>>(Wv_r, Wv_i, Wo_r, Wo_i,
      bWv_r, bWv_i, bWo_r, bWo_i, nDD);
  cvt4_kernel<<<dim3(nDH/2048, 4), blk, 0, stream>>>(W1_r, W1_i, W2_r, W2_i,
      bW1_r, bW1_i, bW2_r, bW2_i, nDH);

  // 1. ln1 (f32 in, bf16 out)
  cln_kernel<<<Mq, blk, 0, stream>>>(x_r, x_i, ln1_gr, ln1_gi, ln1_br, ln1_bi, hr, hi_);
  // 2. Q,K (with fused RoPE), V projections
  cgemm_kernel<0,true ><<<gD, blk, 0, stream>>>(hr, hi_, bWq_r, bWq_i, Qr, Qi,
      nullptr, nullptr, nullptr, nullptr, nullptr, Dq, Dq);
  cgemm_kernel<0,true ><<<gD, blk, 0, stream>>>(hr, hi_, bWk_r, bWk_i, Kr, Ki,
      nullptr, nullptr, nullptr, nullptr, nullptr, Dq, Dq);
  cgemm_kernel<0,false><<<gD, blk, 0, stream>>>(hr, hi_, bWv_r, bWv_i, Vr, Vi,
      nullptr, nullptr, nullptr, nullptr, nullptr, Dq, Dq);
  // 3. attention (writes O over hr/hi)
  attn_kernel<<<Bq*Hq*Lq, blk, 0, stream>>>(Qr, Qi, Kr, Ki, Vr, Vi, Or, Oi);
  // 4. Wo + bias + residual(x, f32) -> ar/ai in d_out (f32)
  cgemm_kernel<1,false><<<gD, blk, 0, stream>>>(Or, Oi, bWo_r, bWo_i, outR, outI,
      bo_r, bo_i, x_r, x_i, nullptr, Dq, Dq);
  // 5. ln2 (f32 in from d_out, bf16 out over Q slots)
  cln_kernel<<<Mq, blk, 0, stream>>>(outR, outI, ln2_gr, ln2_gi, ln2_br, ln2_bi, h2r, h2i);
  // 6. W1 + bias + ModReLU -> f (bf16, over K/V slots)
  cgemm_kernel<2,false><<<gH, blk, 0, stream>>>(h2r, h2i, bW1_r, bW1_i, fr, fi,
      b1_r, b1_i, nullptr, nullptr, mod_b, HIDq, Dq);
  // 7. W2 + bias + residual(ar/ai from d_out) -> d_out in-place (f32)
  cgemm_kernel<3,false><<<gD, blk, 0, stream>>>(fr, fi, bW2_r, bW2_i, outR, outI,
      b2_r, b2_i, outR, outI, nullptr, Dq, HIDq);
}

// Round 4
// 552.368 us; speedup vs baseline: 3.6974x; 3.6974x over previous
//
#include <hip/hip_runtime.h>

#define Bq 2
#define Lq 1024
#define Dq 1024
#define Hq 16
#define HDq 64
#define HIDq 4096
#define Mq (Bq*Lq)   // 2048

typedef __bf16 bf16x8 __attribute__((ext_vector_type(8)));
typedef float floatx4 __attribute__((ext_vector_type(4)));

__device__ __forceinline__ float us2f(unsigned short u){
  unsigned v = ((unsigned)u) << 16;
  return __builtin_bit_cast(float, v);
}
__device__ __forceinline__ unsigned short f2us(float f){
  unsigned u = __builtin_bit_cast(unsigned, f);
  u = u + 0x7fffu + ((u >> 16) & 1u);      // RNE to bf16
  return (unsigned short)(u >> 16);
}

// ---------------- f32 -> bf16 conversion (weights), 4 arrays per launch ----------------
__global__ __launch_bounds__(256) void cvt4_kernel(
    const float* __restrict__ s0, const float* __restrict__ s1,
    const float* __restrict__ s2, const float* __restrict__ s3,
    unsigned short* __restrict__ d0, unsigned short* __restrict__ d1,
    unsigned short* __restrict__ d2, unsigned short* __restrict__ d3,
    int n)
{
  const int a = blockIdx.y;
  const float* s = (a==0) ? s0 : (a==1) ? s1 : (a==2) ? s2 : s3;
  unsigned short* d = (a==0) ? d0 : (a==1) ? d1 : (a==2) ? d2 : d3;
  const int i = (blockIdx.x * 256 + threadIdx.x) * 8;
  if (i >= n) return;
  float4 v0 = ((const float4*)(s + i))[0];
  float4 v1 = ((const float4*)(s + i))[1];
  ushort4 o0, o1;
  o0.x=f2us(v0.x); o0.y=f2us(v0.y); o0.z=f2us(v0.z); o0.w=f2us(v0.w);
  o1.x=f2us(v1.x); o1.y=f2us(v1.y); o1.z=f2us(v1.z); o1.w=f2us(v1.w);
  ((ushort4*)(d + i))[0] = o0;
  ((ushort4*)(d + i))[1] = o1;
}

// ---------------- complex LayerNorm: f32 in, bf16 out; one block per row ----------------
__global__ __launch_bounds__(256) void cln_kernel(
    const float* __restrict__ xr, const float* __restrict__ xi,
    const float* __restrict__ gr, const float* __restrict__ gi,
    const float* __restrict__ br, const float* __restrict__ bi,
    unsigned short* __restrict__ outr, unsigned short* __restrict__ outi)
{
  const int row = blockIdx.x;
  const int t = threadIdx.x;
  const int lane = t & 63, wv = t >> 6;
  __shared__ float sred[8];

  float4 v4r = ((const float4*)(xr + (size_t)row*Dq))[t];
  float4 v4i = ((const float4*)(xi + (size_t)row*Dq))[t];
  float vr[4] = {v4r.x, v4r.y, v4r.z, v4r.w};
  float vi[4] = {v4i.x, v4i.y, v4i.z, v4i.w};
  float sr = vr[0]+vr[1]+vr[2]+vr[3];
  float si = vi[0]+vi[1]+vi[2]+vi[3];
  #pragma unroll
  for (int o=32;o>0;o>>=1){ sr += __shfl_down(sr,o,64); si += __shfl_down(si,o,64); }
  if (lane==0){ sred[wv]=sr; sred[4+wv]=si; }
  __syncthreads();
  float mr = (sred[0]+sred[1]+sred[2]+sred[3]) * (1.0f/Dq);
  float mi = (sred[4]+sred[5]+sred[6]+sred[7]) * (1.0f/Dq);
  float cr[4], ci[4], vs = 0.f;
  #pragma unroll
  for (int j=0;j<4;++j){ cr[j]=vr[j]-mr; ci[j]=vi[j]-mi; vs += cr[j]*cr[j]+ci[j]*ci[j]; }
  #pragma unroll
  for (int o=32;o>0;o>>=1) vs += __shfl_down(vs,o,64);
  __syncthreads();
  if (lane==0) sred[wv]=vs;
  __syncthreads();
  float var = (sred[0]+sred[1]+sred[2]+sred[3]) * (1.0f/Dq);
  float inv = rsqrtf(var + 1e-6f);

  float4 g4r = ((const float4*)gr)[t];
  float4 g4i = ((const float4*)gi)[t];
  float4 b4r = ((const float4*)br)[t];
  float4 b4i = ((const float4*)bi)[t];
  float grf[4] = {g4r.x,g4r.y,g4r.z,g4r.w};
  float gif[4] = {g4i.x,g4i.y,g4i.z,g4i.w};
  float brf[4] = {b4r.x,b4r.y,b4r.z,b4r.w};
  float bif[4] = {b4i.x,b4i.y,b4i.z,b4i.w};
  ushort4 o_r, o_i;
  unsigned short orr[4], oii[4];
  #pragma unroll
  for (int j=0;j<4;++j){
    float nr = cr[j]*inv, ni = ci[j]*inv;
    orr[j] = f2us(nr*grf[j] - ni*gif[j] + brf[j]);
    oii[j] = f2us(nr*gif[j] + ni*grf[j] + bif[j]);
  }
  o_r.x=orr[0]; o_r.y=orr[1]; o_r.z=orr[2]; o_r.w=orr[3];
  o_i.x=oii[0]; o_i.y=oii[1]; o_i.z=oii[2]; o_i.w=oii[3];
  ((ushort4*)(outr + (size_t)row*Dq))[t] = o_r;
  ((ushort4*)(outi + (size_t)row*Dq))[t] = o_i;
}

// ---------------- complex GEMM: C = A @ W^T (complex), MFMA bf16 ----------------
// EPI: 0 plain bf16; 1 +bias+resid(f32)->f32; 2 +bias+ModReLU->bf16; 3 +bias+resid(f32)->f32
template<int EPI, bool ROPE>
__global__ __launch_bounds__(256,2) void cgemm_kernel(
    const unsigned short* __restrict__ Ar, const unsigned short* __restrict__ Ai,
    const unsigned short* __restrict__ Wr, const unsigned short* __restrict__ Wi,
    void* __restrict__ Cr, void* __restrict__ Ci,
    const float* __restrict__ biasR, const float* __restrict__ biasI,
    const float* __restrict__ resR, const float* __restrict__ resI,
    const float* __restrict__ modb,
    int Ndim, int Kdim)
{
  const int t = threadIdx.x;
  const int wv = t >> 6, lane = t & 63;
  const int quad = lane >> 4, l15 = lane & 15;
  const int m0 = blockIdx.x * 64, n0 = blockIdx.y * 64;

  __shared__ __align__(16) unsigned short sAr[64*40], sAi[64*40], sWr[64*40], sWi[64*40];

  floatx4 accRR[4], accII[4], accRI[4], accIR[4];
  floatx4 zero = {0.f,0.f,0.f,0.f};
  #pragma unroll
  for (int i=0;i<4;++i){ accRR[i]=zero; accII[i]=zero; accRI[i]=zero; accIR[i]=zero; }

  const int lr = t >> 2;
  const int lc = (t & 3) * 8;
  const unsigned short* pAr = Ar + (size_t)(m0+lr)*Kdim + lc;
  const unsigned short* pAi = Ai + (size_t)(m0+lr)*Kdim + lc;
  const unsigned short* pWr = Wr + (size_t)(n0+lr)*Kdim + lc;
  const unsigned short* pWi = Wi + (size_t)(n0+lr)*Kdim + lc;
  const int ldso = lr*40 + lc;
  const int arow = wv*16 + l15;

  const int nk = Kdim >> 5;
  for (int kk=0; kk<nk; ++kk){
    uint4 va = *(const uint4*)(pAr + kk*32);
    uint4 vb = *(const uint4*)(pAi + kk*32);
    uint4 vc = *(const uint4*)(pWr + kk*32);
    uint4 vd = *(const uint4*)(pWi + kk*32);
    __syncthreads();
    *(uint4*)&sAr[ldso] = va;
    *(uint4*)&sAi[ldso] = vb;
    *(uint4*)&sWr[ldso] = vc;
    *(uint4*)&sWi[ldso] = vd;
    __syncthreads();
    bf16x8 fAr = *(const bf16x8*)&sAr[arow*40 + quad*8];
    bf16x8 fAi = *(const bf16x8*)&sAi[arow*40 + quad*8];
    #pragma unroll
    for (int tt=0; tt<4; ++tt){
      const int brow = tt*16 + l15;
      bf16x8 fWr = *(const bf16x8*)&sWr[brow*40 + quad*8];
      bf16x8 fWi = *(const bf16x8*)&sWi[brow*40 + quad*8];
      accRR[tt] = __builtin_amdgcn_mfma_f32_16x16x32_bf16(fAr, fWr, accRR[tt], 0,0,0);
      accII[tt] = __builtin_amdgcn_mfma_f32_16x16x32_bf16(fAi, fWi, accII[tt], 0,0,0);
      accRI[tt] = __builtin_amdgcn_mfma_f32_16x16x32_bf16(fAr, fWi, accRI[tt], 0,0,0);
      accIR[tt] = __builtin_amdgcn_mfma_f32_16x16x32_bf16(fAi, fWr, accIR[tt], 0,0,0);
    }
  }

  float cr[4][4], ci[4][4];
  #pragma unroll
  for (int tt=0; tt<4; ++tt)
    #pragma unroll
    for (int r=0; r<4; ++r){
      cr[tt][r] = accRR[tt][r] - accII[tt][r];
      ci[tt][r] = accRI[tt][r] + accIR[tt][r];
    }

  if (ROPE){
    #pragma unroll
    for (int tt=0; tt<2; ++tt){
      const int j = tt*16 + l15;
      const float invf = powf(10000.0f, -(float)j * (1.0f/32.0f));
      #pragma unroll
      for (int r=0; r<4; ++r){
        const int gm = m0 + wv*16 + quad*4 + r;
        const int l = gm & (Lq-1);
        float s, c;
        sincosf((float)l * invf, &s, &c);
        float xr_ = cr[tt][r], yr_ = cr[tt+2][r];
        cr[tt][r]   = xr_*c - yr_*s;
        cr[tt+2][r] = yr_*c + xr_*s;
        float xi_ = ci[tt][r], yi_ = ci[tt+2][r];
        ci[tt][r]   = xi_*c - yi_*s;
        ci[tt+2][r] = yi_*c + xi_*s;
      }
    }
  }

  #pragma unroll
  for (int tt=0; tt<4; ++tt){
    const int gn = n0 + tt*16 + l15;
    float bR = 0.f, bI = 0.f, mb = 0.f;
    if (EPI >= 1){ bR = biasR[gn]; bI = biasI[gn]; }
    if (EPI == 2){ mb = modb[gn]; }
    #pragma unroll
    for (int r=0; r<4; ++r){
      const int gm = m0 + wv*16 + quad*4 + r;
      const size_t idx = (size_t)gm*Ndim + gn;
      float vr_ = cr[tt][r] + bR, vi_ = ci[tt][r] + bI;
      if (EPI == 1 || EPI == 3){ vr_ += resR[idx]; vi_ += resI[idx]; }
      if (EPI == 2){
        float mag = sqrtf(vr_*vr_ + vi_*vi_);
        float safe = (mag > 0.f) ? mag : 1.0f;
        float act = fmaxf(mag + mb, 0.f);
        float sc = act / safe;
        vr_ *= sc; vi_ *= sc;
      }
      if (EPI == 0 || EPI == 2){
        ((unsigned short*)Cr)[idx] = f2us(vr_);
        ((unsigned short*)Ci)[idx] = f2us(vi_);
      } else {
        ((float*)Cr)[idx] = vr_;
        ((float*)Ci)[idx] = vi_;
      }
    }
  }
}

// ---------------- V transpose: V[b,l,h*64+d] -> VT[(b*16+h)*64+d][l] ----------------
__global__ __launch_bounds__(256) void vtrans_kernel(
    const unsigned short* __restrict__ Vr, const unsigned short* __restrict__ Vi,
    unsigned short* __restrict__ VTr, unsigned short* __restrict__ VTi)
{
  const int lt = blockIdx.x;      // 0..15 (L tile)
  const int bh = blockIdx.y;      // 0..31
  const int h = bh & (Hq-1), b = bh >> 4;
  const int t = threadIdx.x;
  __shared__ unsigned short sTr[64*65], sTi[64*65];

  const int row = t >> 2;          // l-local 0..63
  const int dc  = (t & 3) * 16;    // d chunk
  const size_t g = ((size_t)(b*Lq) + lt*64 + row)*Dq + h*HDq + dc;
  uint4 a0 = *(const uint4*)(Vr + g);
  uint4 a1 = *(const uint4*)(Vr + g + 8);
  uint4 b0 = *(const uint4*)(Vi + g);
  uint4 b1 = *(const uint4*)(Vi + g + 8);
  const unsigned short* pa0 = (const unsigned short*)&a0;
  const unsigned short* pa1 = (const unsigned short*)&a1;
  const unsigned short* pb0 = (const unsigned short*)&b0;
  const unsigned short* pb1 = (const unsigned short*)&b1;
  #pragma unroll
  for (int e=0;e<8;++e){
    sTr[(dc+e)*65 + row]   = pa0[e];
    sTr[(dc+8+e)*65 + row] = pa1[e];
    sTi[(dc+e)*65 + row]   = pb0[e];
    sTi[(dc+8+e)*65 + row] = pb1[e];
  }
  __syncthreads();
  const int d  = t >> 2;
  const int lc = (t & 3) * 16;
  unsigned short bufr[16], bufi[16];
  #pragma unroll
  for (int e=0;e<16;++e){
    bufr[e] = sTr[d*65 + lc + e];
    bufi[e] = sTi[d*65 + lc + e];
  }
  const size_t og = ((size_t)bh*HDq + d)*Lq + lt*64 + lc;
  *(uint4*)(VTr + og)     = *(const uint4*)&bufr[0];
  *(uint4*)(VTr + og + 8) = *(const uint4*)&bufr[8];
  *(uint4*)(VTi + og)     = *(const uint4*)&bufi[0];
  *(uint4*)(VTi + og + 8) = *(const uint4*)&bufi[8];
}

// ---------------- flash attention: 64x64 tiles, MFMA, online softmax ----------------
__device__ __forceinline__ int swz(int v){ return v ^ ((v >> 4) & 7); }

__global__ __launch_bounds__(256,2) void fattn_kernel(
    const unsigned short* __restrict__ Qr, const unsigned short* __restrict__ Qi,
    const unsigned short* __restrict__ Kr, const unsigned short* __restrict__ Ki,
    const unsigned short* __restrict__ VTr, const unsigned short* __restrict__ VTi,
    unsigned short* __restrict__ Or, unsigned short* __restrict__ Oi)
{
  const int qt = (int)(gridDim.x - 1 - blockIdx.x);   // big tiles dispatch first
  const int bh = blockIdx.y;
  const int h = bh & (Hq-1), b = bh >> 4;
  const int t = threadIdx.x;
  const int w = t >> 6, lane = t & 63;
  const int quad = lane >> 4, l15 = lane & 15;

  // fragment-linear swizzled tiles (4096 elems each), P round-trip pitch 72
  __shared__ __align__(16) unsigned short sKr[4096], sKi[4096], sVr[4096], sVi[4096];
  __shared__ __align__(16) unsigned short sP[64*72];

  // Q A-fragments: lane m=l15 -> q row w*16+l15; k = d = quad*8+j (lo), +32 (hi)
  const size_t qbase = ((size_t)(b*Lq) + qt*64 + w*16 + l15)*Dq + h*HDq;
  bf16x8 qr_lo = *(const bf16x8*)(Qr + qbase + quad*8);
  bf16x8 qr_hi = *(const bf16x8*)(Qr + qbase + 32 + quad*8);
  bf16x8 qi_lo = *(const bf16x8*)(Qi + qbase + quad*8);
  bf16x8 qi_hi = *(const bf16x8*)(Qi + qbase + 32 + quad*8);

  const floatx4 fzero = {0.f,0.f,0.f,0.f};
  floatx4 aOr[4], aOi[4];
  #pragma unroll
  for (int i=0;i<4;++i){ aOr[i]=fzero; aOi[i]=fzero; }
  float m_run[4] = {-1e30f,-1e30f,-1e30f,-1e30f};
  float l_run[4] = {0.f,0.f,0.f,0.f};

  // staging: thread t covers row (t>>2), 16-elem chunk (t&3)*16 -> frag chunks q8, q8+1
  const int srow = t >> 2;                 // K: kk_local / VT: d
  const int sns  = srow >> 4;              // group 0..3
  const int sl15 = srow & 15;
  const int q8   = (t & 3) * 2;            // 16B-chunk pair
  const int dstA = sns*1024 + swz(q8*16 + sl15)*8;
  const int dstB = sns*1024 + swz((q8+1)*16 + sl15)*8;

  // read offsets (per MFMA step)
  const int rd0 = swz(quad*16 + l15)*8;        // step 0: chunks quad
  const int rd1 = swz((4+quad)*16 + l15)*8;    // step 1: chunks 4+quad

  for (int kt = 0; kt <= qt; ++kt){
    const size_t kg = ((size_t)(b*Lq) + kt*64 + srow)*Dq + h*HDq + q8*8;
    uint4 ka = *(const uint4*)(Kr + kg);
    uint4 kb = *(const uint4*)(Kr + kg + 8);
    uint4 kc = *(const uint4*)(Ki + kg);
    uint4 kd = *(const uint4*)(Ki + kg + 8);
    const size_t vg = ((size_t)bh*HDq + srow)*Lq + kt*64 + q8*8;
    uint4 va = *(const uint4*)(VTr + vg);
    uint4 vb = *(const uint4*)(VTr + vg + 8);
    uint4 vc = *(const uint4*)(VTi + vg);
    uint4 vd = *(const uint4*)(VTi + vg + 8);
    __syncthreads();
    *(uint4*)&sKr[dstA] = ka;  *(uint4*)&sKr[dstB] = kb;
    *(uint4*)&sKi[dstA] = kc;  *(uint4*)&sKi[dstB] = kd;
    *(uint4*)&sVr[dstA] = va;  *(uint4*)&sVr[dstB] = vb;
    *(uint4*)&sVi[dstA] = vc;  *(uint4*)&sVi[dstB] = vd;
    __syncthreads();

    // scores: S[q][kk] = Qr.Kr + Qi.Ki   (4 n-subtiles of 16 kk)
    floatx4 sc[4];
    #pragma unroll
    for (int ns=0; ns<4; ++ns){
      floatx4 x = fzero;
      x = __builtin_amdgcn_mfma_f32_16x16x32_bf16(qr_lo, *(const bf16x8*)&sKr[ns*1024 + rd0], x, 0,0,0);
      x = __builtin_amdgcn_mfma_f32_16x16x32_bf16(qr_hi, *(const bf16x8*)&sKr[ns*1024 + rd1], x, 0,0,0);
      x = __builtin_amdgcn_mfma_f32_16x16x32_bf16(qi_lo, *(const bf16x8*)&sKi[ns*1024 + rd0], x, 0,0,0);
      x = __builtin_amdgcn_mfma_f32_16x16x32_bf16(qi_hi, *(const bf16x8*)&sKi[ns*1024 + rd1], x, 0,0,0);
      sc[ns] = x;
    }

    // scale + causal mask (diag tile only) + row max
    const bool diag = (kt == qt);
    float rmax[4] = {-1e30f,-1e30f,-1e30f,-1e30f};
    #pragma unroll
    for (int ns=0; ns<4; ++ns){
      #pragma unroll
      for (int r=0; r<4; ++r){
        float s = sc[ns][r] * 0.125f;
        if (diag && (ns*16 + l15 > w*16 + quad*4 + r)) s = -1e30f;
        sc[ns][r] = s;
        rmax[r] = fmaxf(rmax[r], s);
      }
    }
    #pragma unroll
    for (int off=1; off<16; off<<=1){
      #pragma unroll
      for (int r=0; r<4; ++r) rmax[r] = fmaxf(rmax[r], __shfl_xor(rmax[r], off, 64));
    }

    float alpha[4], rsum[4];
    #pragma unroll
    for (int r=0; r<4; ++r){
      float mn = fmaxf(m_run[r], rmax[r]);
      alpha[r] = __expf(m_run[r] - mn);
      m_run[r] = mn;
      rsum[r] = 0.f;
    }
    // P = exp(S - m), write to sP rows (this wave's own 16 q rows)
    #pragma unroll
    for (int ns=0; ns<4; ++ns){
      #pragma unroll
      for (int r=0; r<4; ++r){
        float p = __expf(sc[ns][r] - m_run[r]);
        rsum[r] += p;
        sP[(w*16 + quad*4 + r)*72 + ns*16 + l15] = f2us(p);
      }
    }
    #pragma unroll
    for (int off=1; off<16; off<<=1){
      #pragma unroll
      for (int r=0; r<4; ++r) rsum[r] += __shfl_xor(rsum[r], off, 64);
    }
    #pragma unroll
    for (int r=0; r<4; ++r) l_run[r] = l_run[r]*alpha[r] + rsum[r];
    #pragma unroll
    for (int ds=0; ds<4; ++ds)
      #pragma unroll
      for (int r=0; r<4; ++r){ aOr[ds][r] *= alpha[r]; aOi[ds][r] *= alpha[r]; }

    // PV: O[q][d] += P[q][kk] V[kk][d]
    #pragma unroll
    for (int step=0; step<2; ++step){
      bf16x8 pf = *(const bf16x8*)&sP[(w*16 + l15)*72 + step*32 + quad*8];
      const int ro = (step==0) ? rd0 : rd1;
      #pragma unroll
      for (int ds=0; ds<4; ++ds){
        aOr[ds] = __builtin_amdgcn_mfma_f32_16x16x32_bf16(pf, *(const bf16x8*)&sVr[ds*1024 + ro], aOr[ds], 0,0,0);
        aOi[ds] = __builtin_amdgcn_mfma_f32_16x16x32_bf16(pf, *(const bf16x8*)&sVi[ds*1024 + ro], aOi[ds], 0,0,0);
      }
    }
  }

  // epilogue: O /= l
  #pragma unroll
  for (int r=0; r<4; ++r){
    const float il = 1.0f / l_run[r];
    const size_t ob = ((size_t)(b*Lq) + qt*64 + w*16 + quad*4 + r)*Dq + h*HDq;
    #pragma unroll
    for (int ds=0; ds<4; ++ds){
      Or[ob + ds*16 + l15] = f2us(aOr[ds][r] * il);
      Oi[ob + ds*16 + l15] = f2us(aOi[ds][r] * il);
    }
  }
}

// ---------------- launch ----------------
extern "C" void kernel_launch(void* const* d_in, const int* in_sizes, int n_in,
                              void* d_out, int out_size, void* d_ws, size_t ws_size,
                              hipStream_t stream)
{
  const float* x_r    = (const float*)d_in[0];
  const float* x_i    = (const float*)d_in[1];
  const float* Wq_r   = (const float*)d_in[2];
  const float* Wq_i   = (const float*)d_in[3];
  const float* Wk_r   = (const float*)d_in[4];
  const float* Wk_i   = (const float*)d_in[5];
  const float* Wv_r   = (const float*)d_in[6];
  const float* Wv_i   = (const float*)d_in[7];
  const float* Wo_r   = (const float*)d_in[8];
  const float* Wo_i   = (const float*)d_in[9];
  const float* bo_r   = (const float*)d_in[10];
  const float* bo_i   = (const float*)d_in[11];
  const float* ln1_gr = (const float*)d_in[12];
  const float* ln1_gi = (const float*)d_in[13];
  const float* ln1_br = (const float*)d_in[14];
  const float* ln1_bi = (const float*)d_in[15];
  const float* ln2_gr = (const float*)d_in[16];
  const float* ln2_gi = (const float*)d_in[17];
  const float* ln2_br = (const float*)d_in[18];
  const float* ln2_bi = (const float*)d_in[19];
  const float* W1_r   = (const float*)d_in[20];
  const float* W1_i   = (const float*)d_in[21];
  const float* b1_r   = (const float*)d_in[22];
  const float* b1_i   = (const float*)d_in[23];
  const float* W2_r   = (const float*)d_in[24];
  const float* W2_i   = (const float*)d_in[25];
  const float* b2_r   = (const float*)d_in[26];
  const float* b2_i   = (const float*)d_in[27];
  const float* mod_b  = (const float*)d_in[28];

  char* wsb = (char*)d_ws;
  const size_t MB = 1024*1024;
  // --- weights, bf16: 0..48 MB ---
  unsigned short* bWq_r = (unsigned short*)(wsb + 0*MB);
  unsigned short* bWq_i = (unsigned short*)(wsb + 2*MB);
  unsigned short* bWk_r = (unsigned short*)(wsb + 4*MB);
  unsigned short* bWk_i = (unsigned short*)(wsb + 6*MB);
  unsigned short* bWv_r = (unsigned short*)(wsb + 8*MB);
  unsigned short* bWv_i = (unsigned short*)(wsb + 10*MB);
  unsigned short* bWo_r = (unsigned short*)(wsb + 12*MB);
  unsigned short* bWo_i = (unsigned short*)(wsb + 14*MB);
  unsigned short* bW1_r = (unsigned short*)(wsb + 16*MB);
  unsigned short* bW1_i = (unsigned short*)(wsb + 24*MB);
  unsigned short* bW2_r = (unsigned short*)(wsb + 32*MB);
  unsigned short* bW2_i = (unsigned short*)(wsb + 40*MB);
  // --- activations: 48..96 MB ---
  unsigned short* hr  = (unsigned short*)(wsb + 48*MB);
  unsigned short* hi_ = (unsigned short*)(wsb + 52*MB);
  unsigned short* Qr  = (unsigned short*)(wsb + 56*MB);
  unsigned short* Qi  = (unsigned short*)(wsb + 60*MB);
  unsigned short* Kr  = (unsigned short*)(wsb + 64*MB);
  unsigned short* Ki  = (unsigned short*)(wsb + 68*MB);
  unsigned short* Vr  = (unsigned short*)(wsb + 72*MB);
  unsigned short* Vi  = (unsigned short*)(wsb + 76*MB);
  unsigned short* VTr = (unsigned short*)(wsb + 80*MB);
  unsigned short* VTi = (unsigned short*)(wsb + 84*MB);
  unsigned short* Or  = hr;                               // hr/hi dead after QKV gemms
  unsigned short* Oi  = hi_;
  unsigned short* h2r = Qr;                               // Q dead after attn
  unsigned short* h2i = Qi;
  unsigned short* fr  = (unsigned short*)(wsb + 64*MB);   // over K/V (dead after attn)
  unsigned short* fi  = (unsigned short*)(wsb + 80*MB);   // over VT (dead after attn)

  float* outR = (float*)d_out;                            // ar lives here (f32)
  float* outI = outR + (size_t)Mq*Dq;

  const dim3 blk(256);
  const dim3 gD(Mq/64, Dq/64);     // 32 x 16
  const dim3 gH(Mq/64, HIDq/64);   // 32 x 64

  const int nDD = Dq*Dq;
  const int nDH = Dq*HIDq;
  cvt4_kernel<<<dim3(nDD/2048, 4), blk, 0, stream>>>(Wq_r, Wq_i, Wk_r, Wk_i,
      bWq_r, bWq_i, bWk_r, bWk_i, nDD);
  cvt4_kernel<<<dim3(nDD/2048, 4), blk, 0, stream>>>(Wv_r, Wv_i, Wo_r, Wo_i,
      bWv_r, bWv_i, bWo_r, bWo_i, nDD);
  cvt4_kernel<<<dim3(nDH/2048, 4), blk, 0, stream>>>(W1_r, W1_i, W2_r, W2_i,
      bW1_r, bW1_i, bW2_r, bW2_i, nDH);

  // 1. ln1
  cln_kernel<<<Mq, blk, 0, stream>>>(x_r, x_i, ln1_gr, ln1_gi, ln1_br, ln1_bi, hr, hi_);
  // 2. Q,K (fused RoPE), V projections
  cgemm_kernel<0,true ><<<gD, blk, 0, stream>>>(hr, hi_, bWq_r, bWq_i, Qr, Qi,
      nullptr, nullptr, nullptr, nullptr, nullptr, Dq, Dq);
  cgemm_kernel<0,true ><<<gD, blk, 0, stream>>>(hr, hi_, bWk_r, bWk_i, Kr, Ki,
      nullptr, nullptr, nullptr, nullptr, nullptr, Dq, Dq);
  cgemm_kernel<0,false><<<gD, blk, 0, stream>>>(hr, hi_, bWv_r, bWv_i, Vr, Vi,
      nullptr, nullptr, nullptr, nullptr, nullptr, Dq, Dq);
  // 2b. V transpose for PV fragments
  vtrans_kernel<<<dim3(16, 32), blk, 0, stream>>>(Vr, Vi, VTr, VTi);
  // 3. flash attention (writes O over hr/hi)
  fattn_kernel<<<dim3(16, 32), blk, 0, stream>>>(Qr, Qi, Kr, Ki, VTr, VTi, Or, Oi);
  // 4. Wo + bias + residual(x) -> d_out (f32)
  cgemm_kernel<1,false><<<gD, blk, 0, stream>>>(Or, Oi, bWo_r, bWo_i, outR, outI,
      bo_r, bo_i, x_r, x_i, nullptr, Dq, Dq);
  // 5. ln2
  cln_kernel<<<Mq, blk, 0, stream>>>(outR, outI, ln2_gr, ln2_gi, ln2_br, ln2_bi, h2r, h2i);
  // 6. W1 + bias + ModReLU -> f
  cgemm_kernel<2,false><<<gH, blk, 0, stream>>>(h2r, h2i, bW1_r, bW1_i, fr, fi,
      b1_r, b1_i, nullptr, nullptr, mod_b, HIDq, Dq);
  // 7. W2 + bias + residual(d_out) -> d_out in-place (f32)
  cgemm_kernel<3,false><<<gD, blk, 0, stream>>>(fr, fi, bW2_r, bW2_i, outR, outI,
      b2_r, b2_i, outR, outI, nullptr, Dq, HIDq);
}